// Round 10
// baseline (76.036 us; speedup 1.0000x reference)
//
#include <hip/hip_runtime.h>
#include <hip/hip_bf16.h>

// Fused GNN layer: h = x + segment_mean(x[edge_src] by edge_dst); out = relu(h@W + b)
//
// Full path (ws >= ~26.5 MB):
//   prep_full: row_ptr scatter + W bf16 MFMA-pack + x->bf16 (xb) + ZERO ROW at xb[N]
//   main4: 64-thread blocks (1 wave, 16 rows), NO barrier. Quarter-wave owns 4
//          contiguous rows; 2-deep row pipeline of 8-deep gather batches; dummy
//          slots read the zero row (no predication math). Wave-local bf16 MFMA
//          GEMM (16x128 @ 128x128) after lgkmcnt(0).
// Medium path: fp32 gather + rp + pkW. Small path: self-contained.

#define FD  128
#define WR  16     // rows per wave (main4)
#define BRF 64     // rows per block (fallback kernels)
#define HSB 136    // LDS h row stride in bf16 elems

typedef __attribute__((ext_vector_type(8))) short bf16x8;
typedef __attribute__((ext_vector_type(4))) float f32x4;

__device__ __forceinline__ short f2bf(float f) {
    unsigned u = __float_as_uint(f);
    return (short)((u + 0x7FFFu + ((u >> 16) & 1u)) >> 16);   // RNE
}
__device__ __forceinline__ float bf2f(short s) {
    return __uint_as_float(((unsigned)(unsigned short)s) << 16);
}

// ---------------- prep (full): rp + packed W + x->bf16 + zero row ----------------
__global__ __launch_bounds__(256) void prep_full_kernel(
    const float* __restrict__ x, const float* __restrict__ W,
    const int* __restrict__ edst, int* __restrict__ rp,
    short* __restrict__ pkW, short* __restrict__ xb, int N, int E)
{
    const int gid = blockIdx.x * 256 + threadIdx.x;
    const int nth = gridDim.x * 256;

    const int nv = N * FD / 8;
    for (int i = gid; i < nv; i += nth) {
        float4 f0 = *(const float4*)(x + (size_t)i * 8);
        float4 f1 = *(const float4*)(x + (size_t)i * 8 + 4);
        short tmp[8] = {f2bf(f0.x), f2bf(f0.y), f2bf(f0.z), f2bf(f0.w),
                        f2bf(f1.x), f2bf(f1.y), f2bf(f1.z), f2bf(f1.w)};
        *(bf16x8*)(xb + (size_t)i * 8) = *(bf16x8*)tmp;
    }
    if (gid < 16) {   // zero row at index N (dummy-gather target)
        bf16x8 z = {0, 0, 0, 0, 0, 0, 0, 0};
        *(bf16x8*)(xb + (size_t)N * FD + gid * 8) = z;
    }
    for (int e = gid; e < E; e += nth) {
        int cur = edst[e];
        int prev = e ? edst[e - 1] : -1;
        for (int v = prev + 1; v <= cur; ++v) rp[v] = e;
        if (e == E - 1)
            for (int v = cur + 1; v <= N; ++v) rp[v] = E;
    }
    if (E == 0) {
        for (int v = gid; v <= N; v += nth) rp[v] = 0;
    }
    if (gid < 2048) {
        int wv = gid >> 9, rem = gid & 511;
        int ct = rem >> 8, rem2 = rem & 255;
        int kt = rem2 >> 6, lane = rem2 & 63;
        int q = lane >> 4, lr = lane & 15;
        int col = wv * 32 + ct * 16 + lr;
        int k0 = kt * 32 + q * 8;
        short tmp[8];
#pragma unroll
        for (int e2 = 0; e2 < 8; ++e2)
            tmp[e2] = f2bf(W[(size_t)(k0 + e2) * FD + col]);
        *(bf16x8*)(pkW + (size_t)gid * 8) = *(bf16x8*)tmp;
    }
}

// ---------------- main4 helpers ----------------
__device__ __forceinline__ void issue8z(const short* __restrict__ xb, int srcv,
                                        int qb, int ql, int m, int N, uint4 v[8])
{
#pragma unroll
    for (int u = 0; u < 8; ++u) {
        int idx = __shfl(srcv, qb + u);
        if (u >= m) idx = N;                 // dummy -> zero row
        v[u] = *(const uint4*)(xb + (size_t)idx * FD + 8 * ql);
    }
}

__device__ __forceinline__ void acc8z(const uint4 v[8], float2 a[4])
{
#pragma unroll
    for (int u = 0; u < 8; ++u) {
        unsigned w;
        w = v[u].x;
        a[0].x += __uint_as_float(w << 16);
        a[0].y += __uint_as_float(w & 0xFFFF0000u);
        w = v[u].y;
        a[1].x += __uint_as_float(w << 16);
        a[1].y += __uint_as_float(w & 0xFFFF0000u);
        w = v[u].z;
        a[2].x += __uint_as_float(w << 16);
        a[2].y += __uint_as_float(w & 0xFFFF0000u);
        w = v[u].w;
        a[3].x += __uint_as_float(w << 16);
        a[3].y += __uint_as_float(w & 0xFFFF0000u);
    }
}

__device__ __forceinline__ void issue4z(const short* __restrict__ xb, int srcv,
                                        int qb, int ql, int j0, int m, int N, uint4 v[4])
{
#pragma unroll
    for (int u = 0; u < 4; ++u) {
        int jj = j0 + u;
        int idx = __shfl(srcv, qb + (jj & 15));
        if (jj >= m) idx = N;
        v[u] = *(const uint4*)(xb + (size_t)idx * FD + 8 * ql);
    }
}

__device__ __forceinline__ void acc4z(const uint4 v[4], float2 a[4])
{
#pragma unroll
    for (int u = 0; u < 4; ++u) {
        unsigned w;
        w = v[u].x;
        a[0].x += __uint_as_float(w << 16);
        a[0].y += __uint_as_float(w & 0xFFFF0000u);
        w = v[u].y;
        a[1].x += __uint_as_float(w << 16);
        a[1].y += __uint_as_float(w & 0xFFFF0000u);
        w = v[u].z;
        a[2].x += __uint_as_float(w << 16);
        a[2].y += __uint_as_float(w & 0xFFFF0000u);
        w = v[u].w;
        a[3].x += __uint_as_float(w << 16);
        a[3].y += __uint_as_float(w & 0xFFFF0000u);
    }
}

// rare path: degree > 8
__device__ void tailz(const short* __restrict__ xb, const int* __restrict__ esrc,
                      int s, int e, int srcv, int qb, int ql, int N, int E, float2 a[4])
{
    int deg = e - s;
    if (deg <= 8) return;
    uint4 v2[4];
    int m16 = deg < 16 ? deg : 16;
    issue4z(xb, srcv, qb, ql, 8, m16, N, v2);  acc4z(v2, a);
    issue4z(xb, srcv, qb, ql, 12, m16, N, v2); acc4z(v2, a);
    for (int cs = s + 16; cs < e; cs += 16) {
        int m = e - cs; if (m > 16) m = 16;
        int ad = cs + ql; if (ad > E - 1) ad = E - 1;
        int sv = esrc[ad];
        for (int j0 = 0; j0 < m; j0 += 4) {
            issue4z(xb, sv, qb, ql, j0, m, N, v2);
            acc4z(v2, a);
        }
    }
}

__device__ __forceinline__ void finz(short* shb, int rb, int ql,
                                     const bf16x8 xv, const float2 a[4], int deg)
{
    float inv = __builtin_amdgcn_rcpf((float)(deg > 0 ? deg : 1));
    short hb[8];
#pragma unroll
    for (int k = 0; k < 4; ++k) {
        hb[2 * k]     = f2bf(bf2f(xv[2 * k])     + a[k].x * inv);
        hb[2 * k + 1] = f2bf(bf2f(xv[2 * k + 1]) + a[k].y * inv);
    }
    *(bf16x8*)(shb + rb * HSB + 8 * ql) = *(bf16x8*)hb;
}

// ---------------- main4: 1 wave/block, 16 rows, no barrier ----------------
__global__ __launch_bounds__(64) void meanagg_main4_kernel(
    const short* __restrict__ xb, const short* __restrict__ pkW,
    const float* __restrict__ bias, const int* __restrict__ esrc,
    const int* __restrict__ rp, float* __restrict__ out, int N, int E)
{
    __shared__ short shb[WR * HSB];   // 4352 B
    const int lane = threadIdx.x;
    const int qw = lane >> 4, ql = lane & 15, qb = qw << 4;
    const int base = blockIdx.x * WR;
    const int rbase = base + qw * 4;  // this quarter-wave's 4 contiguous rows

    // bounds: 5 loads give s/e for 4 rows (rp monotone)
    int sb[5];
#pragma unroll
    for (int i = 0; i < 5; ++i) {
        int rr = rbase + i; if (rr > N) rr = N;
        sb[i] = rp[rr];
    }
    const int d0 = sb[1] - sb[0], d1 = sb[2] - sb[1];
    const int d2 = sb[3] - sb[2], d3 = sb[4] - sb[3];

    // index batches + self-reads, all issued upfront
    int srcv[4];
    bf16x8 xv[4];
#pragma unroll
    for (int i = 0; i < 4; ++i) {
        int ad = sb[i] + ql; if (ad > E - 1) ad = E - 1; if (ad < 0) ad = 0;
        srcv[i] = esrc[ad];
        int rr = rbase + i; if (rr > N) rr = N;     // pad rows -> zero row
        xv[i] = *(const bf16x8*)(xb + (size_t)rr * FD + 8 * ql);
    }

    uint4 va[8], vb[8];
    issue8z(xb, srcv[0], qb, ql, d0, N, va);
    issue8z(xb, srcv[1], qb, ql, d1, N, vb);

    float2 a[4];

    // row 0 (consume va, refill va with row 2)
    a[0] = a[1] = a[2] = a[3] = make_float2(0.f, 0.f);
    acc8z(va, a);
    issue8z(xb, srcv[2], qb, ql, d2, N, va);
    tailz(xb, esrc, sb[0], sb[1], srcv[0], qb, ql, N, E, a);
    finz(shb, qw * 4 + 0, ql, xv[0], a, d0);

    // row 1 (consume vb, refill vb with row 3)
    a[0] = a[1] = a[2] = a[3] = make_float2(0.f, 0.f);
    acc8z(vb, a);
    issue8z(xb, srcv[3], qb, ql, d3, N, vb);
    tailz(xb, esrc, sb[1], sb[2], srcv[1], qb, ql, N, E, a);
    finz(shb, qw * 4 + 1, ql, xv[1], a, d1);

    // row 2
    a[0] = a[1] = a[2] = a[3] = make_float2(0.f, 0.f);
    acc8z(va, a);
    tailz(xb, esrc, sb[2], sb[3], srcv[2], qb, ql, N, E, a);
    finz(shb, qw * 4 + 2, ql, xv[2], a, d2);

    // row 3
    a[0] = a[1] = a[2] = a[3] = make_float2(0.f, 0.f);
    acc8z(vb, a);
    tailz(xb, esrc, sb[3], sb[4], srcv[3], qb, ql, N, E, a);
    finz(shb, qw * 4 + 3, ql, xv[3], a, d3);

    // wave-local LDS visibility (same wave wrote all 16 rows)
    asm volatile("s_waitcnt lgkmcnt(0)" ::: "memory");

    // GEMM: this wave's 16 rows x all 128 cols
    const int lr = lane & 15, q = lane >> 4;
    bf16x8 af[4];
#pragma unroll
    for (int kt = 0; kt < 4; ++kt)
        af[kt] = *(const bf16x8*)(shb + lr * HSB + kt * 32 + q * 8);

    f32x4 oc[8];
#pragma unroll
    for (int nt = 0; nt < 8; ++nt) oc[nt] = (f32x4){0.f, 0.f, 0.f, 0.f};
#pragma unroll
    for (int nt = 0; nt < 8; ++nt)
#pragma unroll
        for (int kt = 0; kt < 4; ++kt) {
            bf16x8 bf = *(const bf16x8*)(pkW + ((size_t)(nt * 4 + kt) * 64 + lane) * 8);
            oc[nt] = __builtin_amdgcn_mfma_f32_16x16x32_bf16(af[kt], bf, oc[nt], 0, 0, 0);
        }

#pragma unroll
    for (int nt = 0; nt < 8; ++nt) {
        float bv = bias[nt * 16 + lr];
#pragma unroll
        for (int j = 0; j < 4; ++j) {
            int row = base + q * 4 + j;
            if (row < N) {
                float v = oc[nt][j] + bv;
                v = v > 0.f ? v : 0.f;
                out[(size_t)row * FD + nt * 16 + lr] = v;
            }
        }
    }
}

// ---------------- medium path: rp + pkW, fp32 gather ----------------
__global__ __launch_bounds__(256) void prep_kernel(
    const float* __restrict__ W, const int* __restrict__ edst,
    int* __restrict__ rp, short* __restrict__ pkW, int N, int E)
{
    int gid = blockIdx.x * 256 + threadIdx.x;
    if (gid < E) {
        int cur = edst[gid];
        int prev = gid ? edst[gid - 1] : -1;
        for (int v = prev + 1; v <= cur; ++v) rp[v] = gid;
        if (gid == E - 1)
            for (int v = cur + 1; v <= N; ++v) rp[v] = E;
    }
    if (gid < 2048) {
        int wv = gid >> 9, rem = gid & 511;
        int ct = rem >> 8, rem2 = rem & 255;
        int kt = rem2 >> 6, lane = rem2 & 63;
        int q = lane >> 4, lr = lane & 15;
        int col = wv * 32 + ct * 16 + lr;
        int k0 = kt * 32 + q * 8;
        short tmp[8];
#pragma unroll
        for (int e = 0; e < 8; ++e)
            tmp[e] = f2bf(W[(size_t)(k0 + e) * FD + col]);
        *(bf16x8*)(pkW + (size_t)gid * 8) = *(bf16x8*)tmp;
    }
}

__global__ __launch_bounds__(256) void meanagg_main_kernel(
    const float* __restrict__ x, const short* __restrict__ pkW,
    const float* __restrict__ bias, const int* __restrict__ esrc,
    const int* __restrict__ rp, float* __restrict__ out, int N, int E)
{
    __shared__ short shb[BRF * HSB];
    __shared__ int seg[BRF + 1];

    const int t = threadIdx.x;
    const int base = blockIdx.x * BRF;

    if (t < BRF + 1) {
        int idx = base + t;
        seg[t] = rp[idx > N ? N : idx];
    }
    __syncthreads();

    const int wave = t >> 6;
    const int lane = t & 63;
    const int sw = lane >> 5;
    const int sl = lane & 31;
    const int lb = sw << 5;
    const int rowbase = wave * 16;

    for (int it = 0; it < 8; ++it) {
        int cur_rb = rowbase + it * 2 + sw;
        int cur_r  = base + cur_rb;
        if (cur_r >= N) break;
        int cur_s = seg[cur_rb], cur_e = seg[cur_rb + 1];
        float4 a0 = make_float4(0.f, 0.f, 0.f, 0.f), a1 = a0;
        for (int cs = cur_s; cs < cur_e; cs += 32) {
            int m = cur_e - cs; if (m > 32) m = 32;
            int srcv = (cs + sl < cur_e) ? esrc[cs + sl] : 0;
            for (int j0 = 0; j0 < m; j0 += 8) {
                const int rem = m - j0;
#pragma unroll
                for (int u = 0; u < 8; ++u) {
                    int idx = __shfl(srcv, lb + ((j0 + u) & 31));
                    float4 v = *(const float4*)(x + (size_t)idx * FD + 4 * sl);
                    float f = (u < rem) ? 1.f : 0.f;
                    float4* A = (u & 1) ? &a1 : &a0;
                    A->x = fmaf(v.x, f, A->x);
                    A->y = fmaf(v.y, f, A->y);
                    A->z = fmaf(v.z, f, A->z);
                    A->w = fmaf(v.w, f, A->w);
                }
            }
        }
        float4 xvv = *(const float4*)(x + (size_t)cur_r * FD + 4 * sl);
        int deg = cur_e - cur_s;
        float inv = 1.0f / (float)(deg > 0 ? deg : 1);
        short4 hb;
        hb.x = f2bf(xvv.x + (a0.x + a1.x) * inv);
        hb.y = f2bf(xvv.y + (a0.y + a1.y) * inv);
        hb.z = f2bf(xvv.z + (a0.z + a1.z) * inv);
        hb.w = f2bf(xvv.w + (a0.w + a1.w) * inv);
        *(short4*)(shb + cur_rb * HSB + 4 * sl) = hb;
    }
    __syncthreads();

    const int lr = lane & 15;
    const int q  = lane >> 4;
    const int colb = wave * 32;

    bf16x8 bfr[2][4];
#pragma unroll
    for (int ct = 0; ct < 2; ++ct)
#pragma unroll
        for (int kt = 0; kt < 4; ++kt) {
            int f = ((wave * 2 + ct) * 4 + kt) * 64 + lane;
            bfr[ct][kt] = *(const bf16x8*)(pkW + (size_t)f * 8);
        }

    f32x4 acc[4][2];
#pragma unroll
    for (int rt = 0; rt < 4; ++rt) {
        acc[rt][0] = (f32x4){0.f, 0.f, 0.f, 0.f};
        acc[rt][1] = (f32x4){0.f, 0.f, 0.f, 0.f};
    }

#pragma unroll
    for (int rt = 0; rt < 4; ++rt)
#pragma unroll
        for (int kt = 0; kt < 4; ++kt) {
            bf16x8 av = *(const bf16x8*)(shb + (rt * 16 + lr) * HSB + kt * 32 + q * 8);
            acc[rt][0] = __builtin_amdgcn_mfma_f32_16x16x32_bf16(av, bfr[0][kt], acc[rt][0], 0, 0, 0);
            acc[rt][1] = __builtin_amdgcn_mfma_f32_16x16x32_bf16(av, bfr[1][kt], acc[rt][1], 0, 0, 0);
        }

    const float b0 = bias[colb + lr];
    const float b1 = bias[colb + 16 + lr];

#pragma unroll
    for (int rt = 0; rt < 4; ++rt)
#pragma unroll
        for (int j = 0; j < 4; ++j) {
            int row = base + rt * 16 + q * 4 + j;
            if (row < N) {
                float v0 = acc[rt][0][j] + b0; v0 = v0 > 0.f ? v0 : 0.f;
                float v1 = acc[rt][1][j] + b1; v1 = v1 > 0.f ? v1 : 0.f;
                out[(size_t)row * FD + colb + lr]      = v0;
                out[(size_t)row * FD + colb + 16 + lr] = v1;
            }
        }
}

// ---------------- small path: self-contained ----------------
__global__ __launch_bounds__(256) void meanagg_fused_kernel(
    const float* __restrict__ x, const float* __restrict__ W,
    const float* __restrict__ bias, const int* __restrict__ esrc,
    const int* __restrict__ edst, float* __restrict__ out, int N, int E)
{
    __shared__ short shb[BRF * HSB];
    __shared__ int seg[BRF + 1];

    const int t = threadIdx.x;
    const int base = blockIdx.x * BRF;

    if (t < BRF + 1) {
        int v = base + t;
        int lo = 0, hi = E;
        while (lo < hi) {
            int mid = (lo + hi) >> 1;
            if (edst[mid] < v) lo = mid + 1; else hi = mid;
        }
        seg[t] = lo;
    }
    __syncthreads();

    const int wave = t >> 6;
    const int lane = t & 63;
    const int sw = lane >> 5;
    const int sl = lane & 31;
    const int lb = sw << 5;
    const int rowbase = wave * 16;

    for (int it = 0; it < 8; ++it) {
        int cur_rb = rowbase + it * 2 + sw;
        int cur_r  = base + cur_rb;
        if (cur_r >= N) break;
        int cur_s = seg[cur_rb], cur_e = seg[cur_rb + 1];
        float4 a0 = make_float4(0.f, 0.f, 0.f, 0.f), a1 = a0;
        for (int cs = cur_s; cs < cur_e; cs += 32) {
            int m = cur_e - cs; if (m > 32) m = 32;
            int srcv = (cs + sl < cur_e) ? esrc[cs + sl] : 0;
            for (int j0 = 0; j0 < m; j0 += 8) {
                const int rem = m - j0;
#pragma unroll
                for (int u = 0; u < 8; ++u) {
                    int idx = __shfl(srcv, lb + ((j0 + u) & 31));
                    float4 v = *(const float4*)(x + (size_t)idx * FD + 4 * sl);
                    float f = (u < rem) ? 1.f : 0.f;
                    float4* A = (u & 1) ? &a1 : &a0;
                    A->x = fmaf(v.x, f, A->x);
                    A->y = fmaf(v.y, f, A->y);
                    A->z = fmaf(v.z, f, A->z);
                    A->w = fmaf(v.w, f, A->w);
                }
            }
        }
        float4 xvv = *(const float4*)(x + (size_t)cur_r * FD + 4 * sl);
        int deg = cur_e - cur_s;
        float inv = 1.0f / (float)(deg > 0 ? deg : 1);
        short4 hb;
        hb.x = f2bf(xvv.x + (a0.x + a1.x) * inv);
        hb.y = f2bf(xvv.y + (a0.y + a1.y) * inv);
        hb.z = f2bf(xvv.z + (a0.z + a1.z) * inv);
        hb.w = f2bf(xvv.w + (a0.w + a1.w) * inv);
        *(short4*)(shb + cur_rb * HSB + 4 * sl) = hb;
    }
    __syncthreads();

    const int lr = lane & 15;
    const int q  = lane >> 4;
    const int colb = wave * 32;

    bf16x8 bfr[2][4];
#pragma unroll
    for (int ct = 0; ct < 2; ++ct) {
        int col = colb + ct * 16 + lr;
#pragma unroll
        for (int kt = 0; kt < 4; ++kt) {
            bf16x8 f;
#pragma unroll
            for (int e = 0; e < 8; ++e)
                f[e] = f2bf(W[(size_t)(kt * 32 + q * 8 + e) * FD + col]);
            bfr[ct][kt] = f;
        }
    }

    f32x4 acc[4][2];
#pragma unroll
    for (int rt = 0; rt < 4; ++rt) {
        acc[rt][0] = (f32x4){0.f, 0.f, 0.f, 0.f};
        acc[rt][1] = (f32x4){0.f, 0.f, 0.f, 0.f};
    }

#pragma unroll
    for (int rt = 0; rt < 4; ++rt)
#pragma unroll
        for (int kt = 0; kt < 4; ++kt) {
            bf16x8 av = *(const bf16x8*)(shb + (rt * 16 + lr) * HSB + kt * 32 + q * 8);
            acc[rt][0] = __builtin_amdgcn_mfma_f32_16x16x32_bf16(av, bfr[0][kt], acc[rt][0], 0, 0, 0);
            acc[rt][1] = __builtin_amdgcn_mfma_f32_16x16x32_bf16(av, bfr[1][kt], acc[rt][1], 0, 0, 0);
        }

    const float b0 = bias[colb + lr];
    const float b1 = bias[colb + 16 + lr];

#pragma unroll
    for (int rt = 0; rt < 4; ++rt)
#pragma unroll
        for (int j = 0; j < 4; ++j) {
            int row = base + rt * 16 + q * 4 + j;
            if (row < N) {
                float v0 = acc[rt][0][j] + b0; v0 = v0 > 0.f ? v0 : 0.f;
                float v1 = acc[rt][1][j] + b1; v1 = v1 > 0.f ? v1 : 0.f;
                out[(size_t)row * FD + colb + lr]      = v0;
                out[(size_t)row * FD + colb + 16 + lr] = v1;
            }
        }
}

extern "C" void kernel_launch(void* const* d_in, const int* in_sizes, int n_in,
                              void* d_out, int out_size, void* d_ws, size_t ws_size,
                              hipStream_t stream) {
    const float* x    = (const float*)d_in[0];
    const float* W    = (const float*)d_in[1];
    const float* bias = (const float*)d_in[2];
    const int* esrc   = (const int*)d_in[3];
    const int* edst   = (const int*)d_in[4];
    float* out        = (float*)d_out;

    int N = in_sizes[0] / FD;
    int E = in_sizes[3];

    size_t rp_bytes = (size_t)(N + 1) * 4;
    size_t pk_off   = (rp_bytes + 511) & ~(size_t)511;
    size_t xb_off   = (pk_off + 2048 * 8 * 2 + 511) & ~(size_t)511;
    size_t need_med = pk_off + 2048 * 8 * 2;
    size_t need_big = xb_off + (size_t)(N + 1) * FD * 2;   // + zero row

    if (ws_size >= need_big) {
        int* rp    = (int*)d_ws;
        short* pkW = (short*)((char*)d_ws + pk_off);
        short* xb  = (short*)((char*)d_ws + xb_off);
        int blocks = (N + WR - 1) / WR;
        prep_full_kernel<<<2048, 256, 0, stream>>>(x, W, edst, rp, pkW, xb, N, E);
        meanagg_main4_kernel<<<blocks, 64, 0, stream>>>(xb, pkW, bias, esrc, rp, out, N, E);
    } else if (ws_size >= need_med) {
        int* rp    = (int*)d_ws;
        short* pkW = (short*)((char*)d_ws + pk_off);
        int blocks = (N + BRF - 1) / BRF;
        int pblocks = (E + 255) / 256;
        prep_kernel<<<pblocks, 256, 0, stream>>>(W, edst, rp, pkW, N, E);
        meanagg_main_kernel<<<blocks, 256, 0, stream>>>(x, pkW, bias, esrc, rp, out, N, E);
    } else {
        int blocks = (N + BRF - 1) / BRF;
        meanagg_fused_kernel<<<blocks, 256, 0, stream>>>(x, W, bias, esrc, edst, out, N, E);
    }
}

// Round 11
// 61.910 us; speedup vs baseline: 1.2282x; 1.2282x over previous
//
#include <hip/hip_runtime.h>
#include <hip/hip_bf16.h>

// Fused GNN layer: h = x + segment_mean(x[edge_src] by edge_dst); out = relu(h@W + b)
//
// T0 (ws >= ~39 MB): prep(rp + pkW + xb bf16 + xq fp8) -> main5:
//     octet (8 lanes) per row, fp8 gathers (128 B/edge), 8 rows in flight
//     per wave, 2 rows/octet both batches issued upfront; bf16 self + bf16 MFMA GEMM.
// T1 (ws >= ~26.5 MB): prep(no xq) -> main2 (round-8 winner, bf16 gather).
// T2: self-contained single kernel.

#define FD  128
#define BR  64
#define HSB 136    // LDS h row stride in bf16 elems

typedef __attribute__((ext_vector_type(8))) short bf16x8;
typedef __attribute__((ext_vector_type(4))) float f32x4;
typedef __attribute__((ext_vector_type(2))) float f32x2;

__device__ __forceinline__ short f2bf(float f) {
    unsigned u = __float_as_uint(f);
    return (short)((u + 0x7FFFu + ((u >> 16) & 1u)) >> 16);   // RNE
}
__device__ __forceinline__ float bf2f(short s) {
    return __uint_as_float(((unsigned)(unsigned short)s) << 16);
}

// ---- fp8 e4m3 helpers (HW cvt if available; self-consistent SW fallback) ----
#if __has_builtin(__builtin_amdgcn_cvt_pk_f32_fp8) && __has_builtin(__builtin_amdgcn_cvt_pk_fp8_f32)
#define FP8_HW 1
#else
#define FP8_HW 0
#endif

#if !FP8_HW
__device__ __forceinline__ float fp8_to_f(unsigned b) {
    unsigned s = (b >> 7) & 1, e = (b >> 3) & 15, m = b & 7;
    float v = (e == 0) ? ldexpf((float)m, -9) : ldexpf((float)(m + 8), (int)e - 10);
    return s ? -v : v;
}
__device__ __forceinline__ unsigned f_to_fp8(float f) {
    unsigned u = __float_as_uint(f);
    unsigned s = u >> 31;
    u &= 0x7fffffffu;
    if (u > 0x43e00000u) u = 0x43e00000u;   // clamp |f| to 448
    float af = __uint_as_float(u);
    unsigned bits;
    if (af < 7.62939453125e-06f) bits = 0;  // < 2^-17: flush
    else {
        int e; float m = frexpf(af, &e);    // af = m*2^e, m in [0.5,1)
        if (e < -5) {                       // subnormal
            int mi = (int)(af * 512.f + 0.5f);
            bits = (mi > 7) ? 0x08u : (unsigned)mi;
        } else {
            int mi = (int)(m * 16.f + 0.5f);
            int E = e + 6;
            if (mi == 16) { mi = 8; E += 1; }
            if (E > 15) { E = 15; mi = 14; }
            if (E == 15 && mi == 15) mi = 14;   // avoid NaN encoding
            bits = ((unsigned)E << 3) | (unsigned)(mi - 8);
        }
    }
    return bits | (s << 7);
}
#endif

__device__ __forceinline__ f32x2 fp8lo(unsigned w) {
#if FP8_HW
    return __builtin_amdgcn_cvt_pk_f32_fp8(w, false);
#else
    f32x2 r; r.x = fp8_to_f(w & 0xffu); r.y = fp8_to_f((w >> 8) & 0xffu); return r;
#endif
}
__device__ __forceinline__ f32x2 fp8hi(unsigned w) {
#if FP8_HW
    return __builtin_amdgcn_cvt_pk_f32_fp8(w, true);
#else
    f32x2 r; r.x = fp8_to_f((w >> 16) & 0xffu); r.y = fp8_to_f((w >> 24) & 0xffu); return r;
#endif
}
__device__ __forceinline__ unsigned fp8pack4(float a, float b, float c, float d) {
#if FP8_HW
    int w = __builtin_amdgcn_cvt_pk_fp8_f32(a, b, 0, false);
    w = __builtin_amdgcn_cvt_pk_fp8_f32(c, d, w, true);
    return (unsigned)w;
#else
    return f_to_fp8(a) | (f_to_fp8(b) << 8) | (f_to_fp8(c) << 16) | (f_to_fp8(d) << 24);
#endif
}

// ---------------- prep: rp + packed W + xb bf16 (+ optional xq fp8) ----------------
__global__ __launch_bounds__(256) void prep_full_kernel(
    const float* __restrict__ x, const float* __restrict__ W,
    const int* __restrict__ edst, int* __restrict__ rp,
    short* __restrict__ pkW, short* __restrict__ xb,
    unsigned char* __restrict__ xq, int do_q, int N, int E)
{
    const int gid = blockIdx.x * 256 + threadIdx.x;
    const int nth = gridDim.x * 256;

    const int nv = N * FD / 8;
    for (int i = gid; i < nv; i += nth) {
        float4 f0 = *(const float4*)(x + (size_t)i * 8);
        float4 f1 = *(const float4*)(x + (size_t)i * 8 + 4);
        short tmp[8] = {f2bf(f0.x), f2bf(f0.y), f2bf(f0.z), f2bf(f0.w),
                        f2bf(f1.x), f2bf(f1.y), f2bf(f1.z), f2bf(f1.w)};
        *(bf16x8*)(xb + (size_t)i * 8) = *(bf16x8*)tmp;
        if (do_q) {
            uint2 q;
            q.x = fp8pack4(f0.x, f0.y, f0.z, f0.w);
            q.y = fp8pack4(f1.x, f1.y, f1.z, f1.w);
            *(uint2*)(xq + (size_t)i * 8) = q;
        }
    }
    if (gid < 16) {   // zero row at index N
        bf16x8 z = {0, 0, 0, 0, 0, 0, 0, 0};
        *(bf16x8*)(xb + (size_t)N * FD + gid * 8) = z;
        if (do_q) *(uint2*)(xq + (size_t)N * FD + gid * 8) = make_uint2(0u, 0u);
    }
    for (int e = gid; e < E; e += nth) {
        int cur = edst[e];
        int prev = e ? edst[e - 1] : -1;
        for (int v = prev + 1; v <= cur; ++v) rp[v] = e;
        if (e == E - 1)
            for (int v = cur + 1; v <= N; ++v) rp[v] = E;
    }
    if (E == 0)
        for (int v = gid; v <= N; v += nth) rp[v] = 0;
    if (gid < 2048) {
        int wv = gid >> 9, rem = gid & 511;
        int ct = rem >> 8, rem2 = rem & 255;
        int kt = rem2 >> 6, lane = rem2 & 63;
        int q = lane >> 4, lr = lane & 15;
        int col = wv * 32 + ct * 16 + lr;
        int k0 = kt * 32 + q * 8;
        short tmp[8];
#pragma unroll
        for (int e2 = 0; e2 < 8; ++e2)
            tmp[e2] = f2bf(W[(size_t)(k0 + e2) * FD + col]);
        *(bf16x8*)(pkW + (size_t)gid * 8) = *(bf16x8*)tmp;
    }
}

// ---------------- main5 helpers (fp8 gather, octet geometry) ----------------
__device__ __forceinline__ void issue8q(const unsigned char* __restrict__ xq, int srcv,
                                        int ob, int ol, int m, int N, uint4 v[8])
{
#pragma unroll
    for (int u = 0; u < 8; ++u) {
        int idx = __shfl(srcv, ob + u);
        if (u >= m) idx = N;                 // dummy -> zero row
        v[u] = *(const uint4*)(xq + (size_t)idx * FD + 16 * ol);
    }
}

__device__ __forceinline__ void acc8q(const uint4 v[8], f32x2 a[8])
{
#pragma unroll
    for (int u = 0; u < 8; ++u) {
        a[0] += fp8lo(v[u].x); a[1] += fp8hi(v[u].x);
        a[2] += fp8lo(v[u].y); a[3] += fp8hi(v[u].y);
        a[4] += fp8lo(v[u].z); a[5] += fp8hi(v[u].z);
        a[6] += fp8lo(v[u].w); a[7] += fp8hi(v[u].w);
    }
}

__device__ __forceinline__ void issue4q(const unsigned char* __restrict__ xq, int srcv,
                                        int ob, int ol, int j0, int m, int N, uint4 v[4])
{
#pragma unroll
    for (int u = 0; u < 4; ++u) {
        int jj = j0 + u;
        int idx = __shfl(srcv, ob + (jj & 7));
        if (jj >= m) idx = N;
        v[u] = *(const uint4*)(xq + (size_t)idx * FD + 16 * ol);
    }
}

__device__ __forceinline__ void acc4q(const uint4 v[4], f32x2 a[8])
{
#pragma unroll
    for (int u = 0; u < 4; ++u) {
        a[0] += fp8lo(v[u].x); a[1] += fp8hi(v[u].x);
        a[2] += fp8lo(v[u].y); a[3] += fp8hi(v[u].y);
        a[4] += fp8lo(v[u].z); a[5] += fp8hi(v[u].z);
        a[6] += fp8lo(v[u].w); a[7] += fp8hi(v[u].w);
    }
}

__device__ void tailq(const unsigned char* __restrict__ xq, const int* __restrict__ esrc,
                      int s, int e, int ob, int ol, int N, int E, f32x2 a[8])
{
    if (e - s <= 8) return;
    uint4 v2[4];
    for (int cs = s + 8; cs < e; cs += 8) {
        int ad = cs + ol; if (ad > E - 1) ad = E - 1; if (ad < 0) ad = 0;
        int sv = esrc[ad];
        int m = e - cs; if (m > 8) m = 8;
        issue4q(xq, sv, ob, ol, 0, m, N, v2); acc4q(v2, a);
        issue4q(xq, sv, ob, ol, 4, m, N, v2); acc4q(v2, a);
    }
}

__device__ __forceinline__ void finq(short* shb, int rb, int ol,
                                     const bf16x8 xva, const bf16x8 xvb,
                                     const f32x2 a[8], int deg)
{
    float inv = 1.0f / (float)(deg > 0 ? deg : 1);
    short hb[16];
#pragma unroll
    for (int j = 0; j < 8; ++j) {
        short xlo = (j < 4) ? xva[2 * j]     : xvb[2 * (j - 4)];
        short xhi = (j < 4) ? xva[2 * j + 1] : xvb[2 * (j - 4) + 1];
        hb[2 * j]     = f2bf(bf2f(xlo) + a[j].x * inv);
        hb[2 * j + 1] = f2bf(bf2f(xhi) + a[j].y * inv);
    }
    *(bf16x8*)(shb + rb * HSB + 16 * ol)     = *(bf16x8*)hb;
    *(bf16x8*)(shb + rb * HSB + 16 * ol + 8) = *(bf16x8*)(hb + 8);
}

// ---------------- main5: fp8 gather, octet per row, 2 rows/octet ----------------
__global__ __launch_bounds__(256) void meanagg_main5_kernel(
    const short* __restrict__ xb, const unsigned char* __restrict__ xq,
    const short* __restrict__ pkW, const float* __restrict__ bias,
    const int* __restrict__ esrc, const int* __restrict__ rp,
    float* __restrict__ out, int N, int E)
{
    __shared__ short shb[BR * HSB];
    __shared__ int seg[BR + 1];

    const int t = threadIdx.x;
    const int base = blockIdx.x * BR;

    if (t < BR + 1) {
        int idx = base + t;
        seg[t] = rp[idx > N ? N : idx];
    }
    __syncthreads();

    const int wave = t >> 6;
    const int lane = t & 63;
    const int oc = lane >> 3;      // octet 0..7
    const int ol = lane & 7;       // lane in octet: owns features [16ol,16ol+16)
    const int ob = oc << 3;        // shfl lane base

    const int rb0 = wave * 16 + oc;
    const int rb1 = rb0 + 8;
    const int r0c = (base + rb0 > N) ? N : base + rb0;   // clamp pad rows -> zero row
    const int r1c = (base + rb1 > N) ? N : base + rb1;

    const int s0 = seg[rb0], e0 = seg[rb0 + 1];
    const int s1 = seg[rb1], e1 = seg[rb1 + 1];
    const int d0 = e0 - s0, d1 = e1 - s1;

    int ad0 = s0 + ol; if (ad0 > E - 1) ad0 = E - 1; if (ad0 < 0) ad0 = 0;
    int ad1 = s1 + ol; if (ad1 > E - 1) ad1 = E - 1; if (ad1 < 0) ad1 = 0;
    const int srcv0 = esrc[ad0];
    const int srcv1 = esrc[ad1];

    const bf16x8 xv0a = *(const bf16x8*)(xb + (size_t)r0c * FD + 16 * ol);
    const bf16x8 xv0b = *(const bf16x8*)(xb + (size_t)r0c * FD + 16 * ol + 8);
    const bf16x8 xv1a = *(const bf16x8*)(xb + (size_t)r1c * FD + 16 * ol);
    const bf16x8 xv1b = *(const bf16x8*)(xb + (size_t)r1c * FD + 16 * ol + 8);

    // issue BOTH rows' 8-deep fp8 gather batches before consuming anything
    uint4 v0[8], v1[8];
    issue8q(xq, srcv0, ob, ol, d0 < 8 ? d0 : 8, N, v0);
    issue8q(xq, srcv1, ob, ol, d1 < 8 ? d1 : 8, N, v1);

    f32x2 a[8];
#pragma unroll
    for (int p = 0; p < 8; ++p) a[p] = (f32x2){0.f, 0.f};
    acc8q(v0, a);
    tailq(xq, esrc, s0, e0, ob, ol, N, E, a);
    finq(shb, rb0, ol, xv0a, xv0b, a, d0);

#pragma unroll
    for (int p = 0; p < 8; ++p) a[p] = (f32x2){0.f, 0.f};
    acc8q(v1, a);
    tailq(xq, esrc, s1, e1, ob, ol, N, E, a);
    finq(shb, rb1, ol, xv1a, xv1b, a, d1);

    __syncthreads();

    // Phase 2: bf16 MFMA GEMM h[64][128] @ W[128][128] + b, ReLU
    const int lr = lane & 15;
    const int q  = lane >> 4;
    const int colb = wave * 32;

    bf16x8 bfr[2][4];
#pragma unroll
    for (int ct = 0; ct < 2; ++ct)
#pragma unroll
        for (int kt = 0; kt < 4; ++kt) {
            int f = ((wave * 2 + ct) * 4 + kt) * 64 + lane;
            bfr[ct][kt] = *(const bf16x8*)(pkW + (size_t)f * 8);
        }

    f32x4 acc[4][2];
#pragma unroll
    for (int rt = 0; rt < 4; ++rt) {
        acc[rt][0] = (f32x4){0.f, 0.f, 0.f, 0.f};
        acc[rt][1] = (f32x4){0.f, 0.f, 0.f, 0.f};
    }

#pragma unroll
    for (int rt = 0; rt < 4; ++rt)
#pragma unroll
        for (int kt = 0; kt < 4; ++kt) {
            bf16x8 av = *(const bf16x8*)(shb + (rt * 16 + lr) * HSB + kt * 32 + q * 8);
            acc[rt][0] = __builtin_amdgcn_mfma_f32_16x16x32_bf16(av, bfr[0][kt], acc[rt][0], 0, 0, 0);
            acc[rt][1] = __builtin_amdgcn_mfma_f32_16x16x32_bf16(av, bfr[1][kt], acc[rt][1], 0, 0, 0);
        }

    const float b0 = bias[colb + lr];
    const float b1 = bias[colb + 16 + lr];

#pragma unroll
    for (int rt = 0; rt < 4; ++rt)
#pragma unroll
        for (int j = 0; j < 4; ++j) {
            int row = base + rt * 16 + q * 4 + j;
            if (row < N) {
                float o0 = acc[rt][0][j] + b0; o0 = o0 > 0.f ? o0 : 0.f;
                float o1 = acc[rt][1][j] + b1; o1 = o1 > 0.f ? o1 : 0.f;
                out[(size_t)row * FD + colb + lr]      = o0;
                out[(size_t)row * FD + colb + 16 + lr] = o1;
            }
        }
}

// ---------------- T1: round-8 main2 (bf16 gather, quarter-wave per row) ----------------
__global__ __launch_bounds__(256) void meanagg_main2_kernel(
    const short* __restrict__ xb, const short* __restrict__ pkW,
    const float* __restrict__ bias, const int* __restrict__ esrc,
    const int* __restrict__ rp, float* __restrict__ out, int N, int E)
{
    __shared__ short shb[BR * HSB];
    __shared__ int seg[BR + 1];

    const int t = threadIdx.x;
    const int base = blockIdx.x * BR;

    if (t < BR + 1) {
        int idx = base + t;
        seg[t] = rp[idx > N ? N : idx];
    }
    __syncthreads();

    const int wave = t >> 6;
    const int lane = t & 63;
    const int qw = lane >> 4;
    const int ql = lane & 15;
    const int qb = qw << 4;
    const int rowbase = wave * 16;

    {
        int rb0 = rowbase + qw;
        int r0  = base + rb0;
        int s = (r0 < N) ? seg[rb0] : 0;
        int e = (r0 < N) ? seg[rb0 + 1] : 0;
        int srcv_n = (s + ql < e) ? esrc[s + ql] : 0;
        bf16x8 xv_n = {0, 0, 0, 0, 0, 0, 0, 0};
        if (r0 < N) xv_n = *(const bf16x8*)(xb + (size_t)r0 * FD + 8 * ql);

        for (int it = 0; it < 4; ++it) {
            const int cur_rb = rowbase + it * 4 + qw;
            const int cur_r  = base + cur_rb;
            const int cs0 = s, ce = e;
            int srcv = srcv_n;
            const bf16x8 xv = xv_n;

            if (it < 3) {
                int nrb = rowbase + (it + 1) * 4 + qw;
                int nr  = base + nrb;
                s = (nr < N) ? seg[nrb] : 0;
                e = (nr < N) ? seg[nrb + 1] : 0;
                srcv_n = (s + ql < e) ? esrc[s + ql] : 0;
                bf16x8 z = {0, 0, 0, 0, 0, 0, 0, 0};
                xv_n = z;
                if (nr < N) xv_n = *(const bf16x8*)(xb + (size_t)nr * FD + 8 * ql);
            }

            if (cur_r < N) {
                float av[8];
#pragma unroll
                for (int p = 0; p < 8; ++p) av[p] = 0.f;

                for (int cs = cs0; cs < ce; cs += 16) {
                    int m = ce - cs; if (m > 16) m = 16;
                    if (cs != cs0)
                        srcv = (cs + ql < ce) ? esrc[cs + ql] : 0;
                    for (int j0 = 0; j0 < m; j0 += 6) {
                        uint4 v[6];
#pragma unroll
                        for (int u = 0; u < 6; ++u) {
                            int jj = j0 + u;
                            int idx = __shfl(srcv, qb + (jj & 15));
                            if (jj >= m) idx = 0;
                            v[u] = *(const uint4*)(xb + (size_t)idx * FD + 8 * ql);
                        }
#pragma unroll
                        for (int u = 0; u < 6; ++u) {
                            float f = (j0 + u < m) ? 1.f : 0.f;
                            unsigned w;
                            w = v[u].x;
                            av[0] = fmaf(__uint_as_float(w << 16), f, av[0]);
                            av[1] = fmaf(__uint_as_float(w & 0xFFFF0000u), f, av[1]);
                            w = v[u].y;
                            av[2] = fmaf(__uint_as_float(w << 16), f, av[2]);
                            av[3] = fmaf(__uint_as_float(w & 0xFFFF0000u), f, av[3]);
                            w = v[u].z;
                            av[4] = fmaf(__uint_as_float(w << 16), f, av[4]);
                            av[5] = fmaf(__uint_as_float(w & 0xFFFF0000u), f, av[5]);
                            w = v[u].w;
                            av[6] = fmaf(__uint_as_float(w << 16), f, av[6]);
                            av[7] = fmaf(__uint_as_float(w & 0xFFFF0000u), f, av[7]);
                        }
                    }
                }
                int deg = ce - cs0;
                float inv = 1.0f / (float)(deg > 0 ? deg : 1);
                short hb[8];
#pragma unroll
                for (int p = 0; p < 8; ++p)
                    hb[p] = f2bf(bf2f(xv[p]) + av[p] * inv);
                *(bf16x8*)(shb + cur_rb * HSB + 8 * ql) = *(bf16x8*)hb;
            }
        }
    }
    __syncthreads();

    const int lr = lane & 15;
    const int q  = lane >> 4;
    const int colb = wave * 32;

    bf16x8 bfr[2][4];
#pragma unroll
    for (int ct = 0; ct < 2; ++ct)
#pragma unroll
        for (int kt = 0; kt < 4; ++kt) {
            int f = ((wave * 2 + ct) * 4 + kt) * 64 + lane;
            bfr[ct][kt] = *(const bf16x8*)(pkW + (size_t)f * 8);
        }

    f32x4 acc[4][2];
#pragma unroll
    for (int rt = 0; rt < 4; ++rt) {
        acc[rt][0] = (f32x4){0.f, 0.f, 0.f, 0.f};
        acc[rt][1] = (f32x4){0.f, 0.f, 0.f, 0.f};
    }

#pragma unroll
    for (int rt = 0; rt < 4; ++rt)
#pragma unroll
        for (int kt = 0; kt < 4; ++kt) {
            bf16x8 av = *(const bf16x8*)(shb + (rt * 16 + lr) * HSB + kt * 32 + q * 8);
            acc[rt][0] = __builtin_amdgcn_mfma_f32_16x16x32_bf16(av, bfr[0][kt], acc[rt][0], 0, 0, 0);
            acc[rt][1] = __builtin_amdgcn_mfma_f32_16x16x32_bf16(av, bfr[1][kt], acc[rt][1], 0, 0, 0);
        }

    const float b0 = bias[colb + lr];
    const float b1 = bias[colb + 16 + lr];

#pragma unroll
    for (int rt = 0; rt < 4; ++rt)
#pragma unroll
        for (int j = 0; j < 4; ++j) {
            int row = base + rt * 16 + q * 4 + j;
            if (row < N) {
                float v0 = acc[rt][0][j] + b0; v0 = v0 > 0.f ? v0 : 0.f;
                float v1 = acc[rt][1][j] + b1; v1 = v1 > 0.f ? v1 : 0.f;
                out[(size_t)row * FD + colb + lr]      = v0;
                out[(size_t)row * FD + colb + 16 + lr] = v1;
            }
        }
}

// ---------------- T2: self-contained ----------------
__global__ __launch_bounds__(256) void meanagg_fused_kernel(
    const float* __restrict__ x, const float* __restrict__ W,
    const float* __restrict__ bias, const int* __restrict__ esrc,
    const int* __restrict__ edst, float* __restrict__ out, int N, int E)
{
    __shared__ short shb[BR * HSB];
    __shared__ int seg[BR + 1];

    const int t = threadIdx.x;
    const int base = blockIdx.x * BR;

    if (t < BR + 1) {
        int v = base + t;
        int lo = 0, hi = E;
        while (lo < hi) {
            int mid = (lo + hi) >> 1;
            if (edst[mid] < v) lo = mid + 1; else hi = mid;
        }
        seg[t] = lo;
    }
    __syncthreads();

    const int wave = t >> 6;
    const int lane = t & 63;
    const int sw = lane >> 5;
    const int sl = lane & 31;
    const int lb = sw << 5;
    const int rowbase = wave * 16;

    for (int it = 0; it < 8; ++it) {
        int cur_rb = rowbase + it * 2 + sw;
        int cur_r  = base + cur_rb;
        if (cur_r >= N) break;
        int cur_s = seg[cur_rb], cur_e = seg[cur_rb + 1];
        float4 a0 = make_float4(0.f, 0.f, 0.f, 0.f), a1 = a0;
        for (int cs = cur_s; cs < cur_e; cs += 32) {
            int m = cur_e - cs; if (m > 32) m = 32;
            int srcv = (cs + sl < cur_e) ? esrc[cs + sl] : 0;
            for (int j0 = 0; j0 < m; j0 += 8) {
                const int rem = m - j0;
#pragma unroll
                for (int u = 0; u < 8; ++u) {
                    int idx = __shfl(srcv, lb + ((j0 + u) & 31));
                    float4 v = *(const float4*)(x + (size_t)idx * FD + 4 * sl);
                    float f = (u < rem) ? 1.f : 0.f;
                    float4* A = (u & 1) ? &a1 : &a0;
                    A->x = fmaf(v.x, f, A->x);
                    A->y = fmaf(v.y, f, A->y);
                    A->z = fmaf(v.z, f, A->z);
                    A->w = fmaf(v.w, f, A->w);
                }
            }
        }
        float4 xvv = *(const float4*)(x + (size_t)cur_r * FD + 4 * sl);
        int deg = cur_e - cur_s;
        float inv = 1.0f / (float)(deg > 0 ? deg : 1);
        short4 hb;
        hb.x = f2bf(xvv.x + (a0.x + a1.x) * inv);
        hb.y = f2bf(xvv.y + (a0.y + a1.y) * inv);
        hb.z = f2bf(xvv.z + (a0.z + a1.z) * inv);
        hb.w = f2bf(xvv.w + (a0.w + a1.w) * inv);
        *(short4*)(shb + cur_rb * HSB + 4 * sl) = hb;
    }
    __syncthreads();

    const int lr = lane & 15;
    const int q  = lane >> 4;
    const int colb = wave * 32;

    bf16x8 bfr[2][4];
#pragma unroll
    for (int ct = 0; ct < 2; ++ct) {
        int col = colb + ct * 16 + lr;
#pragma unroll
        for (int kt = 0; kt < 4; ++kt) {
            bf16x8 f;
#pragma unroll
            for (int e = 0; e < 8; ++e)
                f[e] = f2bf(W[(size_t)(kt * 32 + q * 8 + e) * FD + col]);
            bfr[ct][kt] = f;
        }
    }

    f32x4 acc[4][2];
#pragma unroll
    for (int rt = 0; rt < 4; ++rt) {
        acc[rt][0] = (f32x4){0.f, 0.f, 0.f, 0.f};
        acc[rt][1] = (f32x4){0.f, 0.f, 0.f, 0.f};
    }

#pragma unroll
    for (int rt = 0; rt < 4; ++rt)
#pragma unroll
        for (int kt = 0; kt < 4; ++kt) {
            bf16x8 av = *(const bf16x8*)(shb + (rt * 16 + lr) * HSB + kt * 32 + q * 8);
            acc[rt][0] = __builtin_amdgcn_mfma_f32_16x16x32_bf16(av, bfr[0][kt], acc[rt][0], 0, 0, 0);
            acc[rt][1] = __builtin_amdgcn_mfma_f32_16x16x32_bf16(av, bfr[1][kt], acc[rt][1], 0, 0, 0);
        }

    const float b0 = bias[colb + lr];
    const float b1 = bias[colb + 16 + lr];

#pragma unroll
    for (int rt = 0; rt < 4; ++rt)
#pragma unroll
        for (int j = 0; j < 4; ++j) {
            int row = base + rt * 16 + q * 4 + j;
            if (row < N) {
                float v0 = acc[rt][0][j] + b0; v0 = v0 > 0.f ? v0 : 0.f;
                float v1 = acc[rt][1][j] + b1; v1 = v1 > 0.f ? v1 : 0.f;
                out[(size_t)row * FD + colb + lr]      = v0;
                out[(size_t)row * FD + colb + 16 + lr] = v1;
            }
        }
}

extern "C" void kernel_launch(void* const* d_in, const int* in_sizes, int n_in,
                              void* d_out, int out_size, void* d_ws, size_t ws_size,
                              hipStream_t stream) {
    const float* x    = (const float*)d_in[0];
    const float* W    = (const float*)d_in[1];
    const float* bias = (const float*)d_in[2];
    const int* esrc   = (const int*)d_in[3];
    const int* edst   = (const int*)d_in[4];
    float* out        = (float*)d_out;

    int N = in_sizes[0] / FD;
    int E = in_sizes[3];
    int blocks = (N + BR - 1) / BR;

    size_t rp_bytes = (size_t)(N + 1) * 4;
    size_t pk_off   = (rp_bytes + 511) & ~(size_t)511;
    size_t xb_off   = (pk_off + 2048 * 8 * 2 + 511) & ~(size_t)511;
    size_t xq_off   = (xb_off + (size_t)(N + 1) * FD * 2 + 511) & ~(size_t)511;
    size_t need_t1  = xb_off + (size_t)(N + 1) * FD * 2;
    size_t need_t0  = xq_off + (size_t)(N + 1) * FD;

    if (ws_size >= need_t0) {
        int* rp    = (int*)d_ws;
        short* pkW = (short*)((char*)d_ws + pk_off);
        short* xb  = (short*)((char*)d_ws + xb_off);
        unsigned char* xq = (unsigned char*)((char*)d_ws + xq_off);
        prep_full_kernel<<<2048, 256, 0, stream>>>(x, W, edst, rp, pkW, xb, xq, 1, N, E);
        meanagg_main5_kernel<<<blocks, 256, 0, stream>>>(xb, xq, pkW, bias, esrc, rp, out, N, E);
    } else if (ws_size >= need_t1) {
        int* rp    = (int*)d_ws;
        short* pkW = (short*)((char*)d_ws + pk_off);
        short* xb  = (short*)((char*)d_ws + xb_off);
        prep_full_kernel<<<2048, 256, 0, stream>>>(x, W, edst, rp, pkW, xb, (unsigned char*)xb, 0, N, E);
        meanagg_main2_kernel<<<blocks, 256, 0, stream>>>(xb, pkW, bias, esrc, rp, out, N, E);
    } else {
        meanagg_fused_kernel<<<blocks, 256, 0, stream>>>(x, W, bias, esrc, edst, out, N, E);
    }
}

// Round 12
// 58.449 us; speedup vs baseline: 1.3009x; 1.0592x over previous
//
#include <hip/hip_runtime.h>
#include <hip/hip_bf16.h>

// Fused GNN layer, restructured via linearity:
//   relu((x + mean_src(x))W + b) = relu(z + mean_src(z) + b),  z = x@W
//
// T0 (ws >= ~26 MB):
//   K1 gemm_z: rp scatter + z = bf16(x@W) coalesced to ws (+ zero row at z[N])
//   K2 agg: quarter-wave per row, bf16 gathers of z[src], + z[self] + bias,
//           relu, direct fp32 store. No GEMM, no LDS tile, no end barrier.
// T2: self-contained single kernel (binary search + inline W pack).

#define FD  128
#define BR  64
#define HSB 136    // LDS row stride in bf16 elems (K1 tile)

typedef __attribute__((ext_vector_type(8))) short bf16x8;
typedef __attribute__((ext_vector_type(4))) float f32x4;

__device__ __forceinline__ short f2bf(float f) {
    unsigned u = __float_as_uint(f);
    return (short)((u + 0x7FFFu + ((u >> 16) & 1u)) >> 16);   // RNE
}
__device__ __forceinline__ float bf2f(short s) {
    return __uint_as_float(((unsigned)(unsigned short)s) << 16);
}

// ---------------- K1: rp scatter + z = bf16(x@W) ----------------
__global__ __launch_bounds__(256) void gemm_z_kernel(
    const float* __restrict__ x, const float* __restrict__ W,
    const int* __restrict__ edst, int* __restrict__ rp,
    short* __restrict__ zb, int N, int E)
{
    __shared__ short sh[BR * HSB];   // 17408 B
    const int t = threadIdx.x;
    const int base = blockIdx.x * BR;

    // rp scatter (edge_dst sorted), grid-stride
    for (int e = blockIdx.x * 256 + t; e < E; e += gridDim.x * 256) {
        int cur = edst[e];
        int prev = e ? edst[e - 1] : -1;
        for (int v = prev + 1; v <= cur; ++v) rp[v] = e;
        if (e == E - 1)
            for (int v = cur + 1; v <= N; ++v) rp[v] = E;
    }
    if (E == 0)
        for (int v = blockIdx.x * 256 + t; v <= N; v += gridDim.x * 256) rp[v] = 0;
    if (blockIdx.x == 0 && t < 16) {   // zero row at zb[N]
        bf16x8 z = {0, 0, 0, 0, 0, 0, 0, 0};
        *(bf16x8*)(zb + (size_t)N * FD + t * 8) = z;
    }

    // stage x tile (64x128 fp32) -> bf16 LDS, coalesced
#pragma unroll
    for (int i = 0; i < 8; ++i) {
        int off = i * 1024 + t * 4;           // element offset in tile
        int row = off >> 7, col = off & 127;
        int gr = base + row;
        float4 v = (gr < N) ? *(const float4*)(x + (size_t)gr * FD + col)
                            : make_float4(0.f, 0.f, 0.f, 0.f);
        short4 s4;
        s4.x = f2bf(v.x); s4.y = f2bf(v.y); s4.z = f2bf(v.z); s4.w = f2bf(v.w);
        *(short4*)(sh + row * HSB + col) = s4;
    }
    __syncthreads();

    // GEMM: wave owns 32 cols; W fragments assembled inline (L2-hot)
    const int wave = t >> 6, lane = t & 63;
    const int lr = lane & 15, q = lane >> 4;
    const int colb = wave * 32;

    bf16x8 bfr[2][4];
#pragma unroll
    for (int ct = 0; ct < 2; ++ct) {
        int col = colb + ct * 16 + lr;
#pragma unroll
        for (int kt = 0; kt < 4; ++kt) {
            bf16x8 f;
#pragma unroll
            for (int e = 0; e < 8; ++e)
                f[e] = f2bf(W[(size_t)(kt * 32 + q * 8 + e) * FD + col]);
            bfr[ct][kt] = f;
        }
    }

    f32x4 acc[4][2];
#pragma unroll
    for (int rt = 0; rt < 4; ++rt) {
        acc[rt][0] = (f32x4){0.f, 0.f, 0.f, 0.f};
        acc[rt][1] = (f32x4){0.f, 0.f, 0.f, 0.f};
    }
#pragma unroll
    for (int rt = 0; rt < 4; ++rt)
#pragma unroll
        for (int kt = 0; kt < 4; ++kt) {
            bf16x8 av = *(const bf16x8*)(sh + (rt * 16 + lr) * HSB + kt * 32 + q * 8);
            acc[rt][0] = __builtin_amdgcn_mfma_f32_16x16x32_bf16(av, bfr[0][kt], acc[rt][0], 0, 0, 0);
            acc[rt][1] = __builtin_amdgcn_mfma_f32_16x16x32_bf16(av, bfr[1][kt], acc[rt][1], 0, 0, 0);
        }

    __syncthreads();   // all A-reads done before overwriting sh with C

    // C -> bf16 into sh (C layout: col = colb+ct*16+lr, row = rt*16 + q*4 + j)
#pragma unroll
    for (int rt = 0; rt < 4; ++rt)
#pragma unroll
        for (int ct = 0; ct < 2; ++ct)
#pragma unroll
            for (int j = 0; j < 4; ++j)
                sh[(rt * 16 + q * 4 + j) * HSB + colb + ct * 16 + lr] = f2bf(acc[rt][ct][j]);
    __syncthreads();

    // coalesced bf16 store of z tile
#pragma unroll
    for (int i = 0; i < 4; ++i) {
        int off = i * 2048 + t * 8;
        int row = off >> 7, col = off & 127;
        int gr = base + row;
        if (gr < N)
            *(bf16x8*)(zb + (size_t)gr * FD + col) = *(const bf16x8*)(sh + row * HSB + col);
    }
}

// ---------------- K2: gather-mean epilogue (no GEMM, no barrier convoy) ----------------
__global__ __launch_bounds__(256) void agg_kernel(
    const short* __restrict__ zb, const float* __restrict__ bias,
    const int* __restrict__ esrc, const int* __restrict__ rp,
    float* __restrict__ out, int N, int E)
{
    __shared__ int seg[BR + 1];
    const int t = threadIdx.x;
    const int base = blockIdx.x * BR;

    if (t < BR + 1) {
        int idx = base + t;
        seg[t] = rp[idx > N ? N : idx];
    }
    __syncthreads();

    const int wave = t >> 6, lane = t & 63;
    const int qw = lane >> 4, ql = lane & 15, qb = qw << 4;
    const int rowbase = wave * 16;

    // bias for my 8 columns (L1-hot)
    const float4 bja = *(const float4*)(bias + 8 * ql);
    const float4 bjb = *(const float4*)(bias + 8 * ql + 4);

    // prologue: prefetch it=0
    int rb0 = rowbase + qw;
    int r0  = base + rb0;
    int s = (r0 < N) ? seg[rb0] : 0;
    int e = (r0 < N) ? seg[rb0 + 1] : 0;
    int srcv_n = (s + ql < e) ? esrc[s + ql] : 0;
    bf16x8 zv_n = {0, 0, 0, 0, 0, 0, 0, 0};
    if (r0 < N) zv_n = *(const bf16x8*)(zb + (size_t)r0 * FD + 8 * ql);

    for (int it = 0; it < 4; ++it) {
        const int cur_rb = rowbase + it * 4 + qw;
        const int cur_r  = base + cur_rb;
        const int cs0 = s, ce = e;
        int srcv = srcv_n;
        const bf16x8 zv = zv_n;

        // prefetch next iteration (indices + self row)
        if (it < 3) {
            int nrb = rowbase + (it + 1) * 4 + qw;
            int nr  = base + nrb;
            s = (nr < N) ? seg[nrb] : 0;
            e = (nr < N) ? seg[nrb + 1] : 0;
            srcv_n = (s + ql < e) ? esrc[s + ql] : 0;
            bf16x8 z = {0, 0, 0, 0, 0, 0, 0, 0};
            zv_n = z;
            if (nr < N) zv_n = *(const bf16x8*)(zb + (size_t)nr * FD + 8 * ql);
        }

        if (cur_r < N) {
            float av[8];
#pragma unroll
            for (int p = 0; p < 8; ++p) av[p] = 0.f;

            for (int cs = cs0; cs < ce; cs += 16) {
                int m = ce - cs; if (m > 16) m = 16;
                if (cs != cs0)   // deg > 16: reload index batch
                    srcv = (cs + ql < ce) ? esrc[cs + ql] : 0;
                for (int j0 = 0; j0 < m; j0 += 8) {
                    uint4 v[8];
#pragma unroll
                    for (int u = 0; u < 8; ++u) {
                        int jj = j0 + u;
                        int idx = __shfl(srcv, qb + (jj & 15));
                        if (jj >= m) idx = N;   // dummy -> zero row
                        v[u] = *(const uint4*)(zb + (size_t)idx * FD + 8 * ql);
                    }
#pragma unroll
                    for (int u = 0; u < 8; ++u) {
                        unsigned w;
                        w = v[u].x;
                        av[0] += __uint_as_float(w << 16);
                        av[1] += __uint_as_float(w & 0xFFFF0000u);
                        w = v[u].y;
                        av[2] += __uint_as_float(w << 16);
                        av[3] += __uint_as_float(w & 0xFFFF0000u);
                        w = v[u].z;
                        av[4] += __uint_as_float(w << 16);
                        av[5] += __uint_as_float(w & 0xFFFF0000u);
                        w = v[u].w;
                        av[6] += __uint_as_float(w << 16);
                        av[7] += __uint_as_float(w & 0xFFFF0000u);
                    }
                }
            }
            int deg = ce - cs0;
            float inv = 1.0f / (float)(deg > 0 ? deg : 1);
            float o[8];
            o[0] = bf2f(zv[0]) + av[0] * inv + bja.x;
            o[1] = bf2f(zv[1]) + av[1] * inv + bja.y;
            o[2] = bf2f(zv[2]) + av[2] * inv + bja.z;
            o[3] = bf2f(zv[3]) + av[3] * inv + bja.w;
            o[4] = bf2f(zv[4]) + av[4] * inv + bjb.x;
            o[5] = bf2f(zv[5]) + av[5] * inv + bjb.y;
            o[6] = bf2f(zv[6]) + av[6] * inv + bjb.z;
            o[7] = bf2f(zv[7]) + av[7] * inv + bjb.w;
#pragma unroll
            for (int p = 0; p < 8; ++p) o[p] = o[p] > 0.f ? o[p] : 0.f;
            *(float4*)(out + (size_t)cur_r * FD + 8 * ql)     = make_float4(o[0], o[1], o[2], o[3]);
            *(float4*)(out + (size_t)cur_r * FD + 8 * ql + 4) = make_float4(o[4], o[5], o[6], o[7]);
        }
    }
}

// ---------------- T2: self-contained fallback ----------------
__global__ __launch_bounds__(256) void meanagg_fused_kernel(
    const float* __restrict__ x, const float* __restrict__ W,
    const float* __restrict__ bias, const int* __restrict__ esrc,
    const int* __restrict__ edst, float* __restrict__ out, int N, int E)
{
    __shared__ short shb[BR * HSB];
    __shared__ int seg[BR + 1];

    const int t = threadIdx.x;
    const int base = blockIdx.x * BR;

    if (t < BR + 1) {
        int v = base + t;
        int lo = 0, hi = E;
        while (lo < hi) {
            int mid = (lo + hi) >> 1;
            if (edst[mid] < v) lo = mid + 1; else hi = mid;
        }
        seg[t] = lo;
    }
    __syncthreads();

    const int wave = t >> 6;
    const int lane = t & 63;
    const int sw = lane >> 5;
    const int sl = lane & 31;
    const int lb = sw << 5;
    const int rowbase = wave * 16;

    for (int it = 0; it < 8; ++it) {
        int cur_rb = rowbase + it * 2 + sw;
        int cur_r  = base + cur_rb;
        if (cur_r >= N) break;
        int cur_s = seg[cur_rb], cur_e = seg[cur_rb + 1];
        float4 a0 = make_float4(0.f, 0.f, 0.f, 0.f), a1 = a0;
        for (int cs = cur_s; cs < cur_e; cs += 32) {
            int m = cur_e - cs; if (m > 32) m = 32;
            int srcv = (cs + sl < cur_e) ? esrc[cs + sl] : 0;
            for (int j0 = 0; j0 < m; j0 += 8) {
                const int rem = m - j0;
#pragma unroll
                for (int u = 0; u < 8; ++u) {
                    int idx = __shfl(srcv, lb + ((j0 + u) & 31));
                    float4 v = *(const float4*)(x + (size_t)idx * FD + 4 * sl);
                    float f = (u < rem) ? 1.f : 0.f;
                    float4* A = (u & 1) ? &a1 : &a0;
                    A->x = fmaf(v.x, f, A->x);
                    A->y = fmaf(v.y, f, A->y);
                    A->z = fmaf(v.z, f, A->z);
                    A->w = fmaf(v.w, f, A->w);
                }
            }
        }
        float4 xvv = *(const float4*)(x + (size_t)cur_r * FD + 4 * sl);
        int deg = cur_e - cur_s;
        float inv = 1.0f / (float)(deg > 0 ? deg : 1);
        short4 hb;
        hb.x = f2bf(xvv.x + (a0.x + a1.x) * inv);
        hb.y = f2bf(xvv.y + (a0.y + a1.y) * inv);
        hb.z = f2bf(xvv.z + (a0.z + a1.z) * inv);
        hb.w = f2bf(xvv.w + (a0.w + a1.w) * inv);
        *(short4*)(shb + cur_rb * HSB + 4 * sl) = hb;
    }
    __syncthreads();

    const int lr = lane & 15;
    const int q  = lane >> 4;
    const int colb = wave * 32;

    bf16x8 bfr[2][4];
#pragma unroll
    for (int ct = 0; ct < 2; ++ct) {
        int col = colb + ct * 16 + lr;
#pragma unroll
        for (int kt = 0; kt < 4; ++kt) {
            bf16x8 f;
#pragma unroll
            for (int e = 0; e < 8; ++e)
                f[e] = f2bf(W[(size_t)(kt * 32 + q * 8 + e) * FD + col]);
            bfr[ct][kt] = f;
        }
    }

    f32x4 acc[4][2];
#pragma unroll
    for (int rt = 0; rt < 4; ++rt) {
        acc[rt][0] = (f32x4){0.f, 0.f, 0.f, 0.f};
        acc[rt][1] = (f32x4){0.f, 0.f, 0.f, 0.f};
    }
#pragma unroll
    for (int rt = 0; rt < 4; ++rt)
#pragma unroll
        for (int kt = 0; kt < 4; ++kt) {
            bf16x8 av = *(const bf16x8*)(shb + (rt * 16 + lr) * HSB + kt * 32 + q * 8);
            acc[rt][0] = __builtin_amdgcn_mfma_f32_16x16x32_bf16(av, bfr[0][kt], acc[rt][0], 0, 0, 0);
            acc[rt][1] = __builtin_amdgcn_mfma_f32_16x16x32_bf16(av, bfr[1][kt], acc[rt][1], 0, 0, 0);
        }

    const float b0 = bias[colb + lr];
    const float b1 = bias[colb + 16 + lr];

#pragma unroll
    for (int rt = 0; rt < 4; ++rt)
#pragma unroll
        for (int j = 0; j < 4; ++j) {
            int row = base + rt * 16 + q * 4 + j;
            if (row < N) {
                float v0 = acc[rt][0][j] + b0; v0 = v0 > 0.f ? v0 : 0.f;
                float v1 = acc[rt][1][j] + b1; v1 = v1 > 0.f ? v1 : 0.f;
                out[(size_t)row * FD + colb + lr]      = v0;
                out[(size_t)row * FD + colb + 16 + lr] = v1;
            }
        }
}

extern "C" void kernel_launch(void* const* d_in, const int* in_sizes, int n_in,
                              void* d_out, int out_size, void* d_ws, size_t ws_size,
                              hipStream_t stream) {
    const float* x    = (const float*)d_in[0];
    const float* W    = (const float*)d_in[1];
    const float* bias = (const float*)d_in[2];
    const int* esrc   = (const int*)d_in[3];
    const int* edst   = (const int*)d_in[4];
    float* out        = (float*)d_out;

    int N = in_sizes[0] / FD;
    int E = in_sizes[3];
    int blocks = (N + BR - 1) / BR;

    size_t rp_bytes = (size_t)(N + 1) * 4;
    size_t zb_off   = (rp_bytes + 511) & ~(size_t)511;
    size_t need     = zb_off + (size_t)(N + 1) * FD * 2;   // rp + zb (+ zero row)

    if (ws_size >= need) {
        int* rp   = (int*)d_ws;
        short* zb = (short*)((char*)d_ws + zb_off);
        gemm_z_kernel<<<blocks, 256, 0, stream>>>(x, W, edst, rp, zb, N, E);
        agg_kernel<<<blocks, 256, 0, stream>>>(zb, bias, esrc, rp, out, N, E);
    } else {
        meanagg_fused_kernel<<<blocks, 256, 0, stream>>>(x, W, bias, esrc, edst, out, N, E);
    }
}